// Round 1
// baseline (80.555 us; speedup 1.0000x reference)
//
#include <hip/hip_runtime.h>
#include <math.h>

static constexpr int Bn = 64, Mn = 50, Cn = 4;

// ws float layout:
//  0..2  : focal base sums per scale (t=0 over all cls elements)
//  3..5  : obj base sums per scale   (t=0 over all obj elements)
//  6..8  : cls corrections (focal(x,1)-focal(x,0) at unique (label,cell))
//  9..11 : obj corrections (1.5*sp(-x)-sp(x) at unique cell)
// 12..14 : reg sums (smooth_l1 at unique cell, last-box-wins targets)
// 15..17 : denom (4 per unique cell)

__device__ __forceinline__ float focal0_4(float4 v) {
  float s = 0.f;
  const float* px = &v.x;
#pragma unroll
  for (int k = 0; k < 4; ++k) {
    float x = px[k];
    float e = expf(-fabsf(x));
    float sp = fmaxf(x, 0.f) + log1pf(e);          // softplus(x) == bce(t=0)
    float p = (x >= 0.f) ? 1.f / (1.f + e) : e / (1.f + e);  // sigmoid(x)
    s += 0.75f * p * p * sp;
  }
  return s;
}

__device__ __forceinline__ float obj0_4(float4 v) {
  float s = 0.f;
  const float* px = &v.x;
#pragma unroll
  for (int k = 0; k < 4; ++k) {
    float x = px[k];
    s += fmaxf(x, 0.f) + log1pf(expf(-fabsf(x)));  // softplus(x)
  }
  return s;
}

__device__ __forceinline__ float wave_reduce(float v) {
#pragma unroll
  for (int off = 32; off > 0; off >>= 1) v += __shfl_down(v, off, 64);
  return v;
}

__global__ __launch_bounds__(256) void base_kernel(
    const float4* __restrict__ c3, const float4* __restrict__ c4, const float4* __restrict__ c5,
    const float4* __restrict__ o3, const float4* __restrict__ o4, const float4* __restrict__ o5,
    float* __restrict__ ws) {
  // sizes in float4 units
  constexpr unsigned N_C3 = Bn * Cn * 160u * 160u / 4;  // 1,638,400
  constexpr unsigned N_C4 = Bn * Cn * 80u * 80u / 4;    //   409,600
  constexpr unsigned N_C5 = Bn * Cn * 40u * 40u / 4;    //   102,400
  constexpr unsigned N_O3 = Bn * 160u * 160u / 4;       //   409,600
  constexpr unsigned N_O4 = Bn * 80u * 80u / 4;         //   102,400
  constexpr unsigned N_O5 = Bn * 40u * 40u / 4;         //    25,600
  constexpr unsigned B0 = N_C3;
  constexpr unsigned B1 = B0 + N_C4;
  constexpr unsigned B2 = B1 + N_C5;
  constexpr unsigned B3 = B2 + N_O3;
  constexpr unsigned B4 = B3 + N_O4;
  constexpr unsigned TOTAL = B4 + N_O5;                 // 2,688,000

  unsigned gid = blockIdx.x * blockDim.x + threadIdx.x;
  unsigned gstride = gridDim.x * blockDim.x;

  float a0 = 0.f, a1 = 0.f, a2 = 0.f, a3 = 0.f, a4 = 0.f, a5 = 0.f;
  for (unsigned i = gid; i < TOTAL; i += gstride) {
    if (i < B0)       a0 += focal0_4(c3[i]);
    else if (i < B1)  a1 += focal0_4(c4[i - B0]);
    else if (i < B2)  a2 += focal0_4(c5[i - B1]);
    else if (i < B3)  a3 += obj0_4(o3[i - B2]);
    else if (i < B4)  a4 += obj0_4(o4[i - B3]);
    else              a5 += obj0_4(o5[i - B4]);
  }

  a0 = wave_reduce(a0); a1 = wave_reduce(a1); a2 = wave_reduce(a2);
  a3 = wave_reduce(a3); a4 = wave_reduce(a4); a5 = wave_reduce(a5);

  __shared__ float sdata[6][4];
  int lane = threadIdx.x & 63;
  int wid = threadIdx.x >> 6;
  if (lane == 0) {
    sdata[0][wid] = a0; sdata[1][wid] = a1; sdata[2][wid] = a2;
    sdata[3][wid] = a3; sdata[4][wid] = a4; sdata[5][wid] = a5;
  }
  __syncthreads();
  if (threadIdx.x < 6) {
    float s = sdata[threadIdx.x][0] + sdata[threadIdx.x][1] +
              sdata[threadIdx.x][2] + sdata[threadIdx.x][3];
    atomicAdd(&ws[threadIdx.x], s);
  }
}

__global__ __launch_bounds__(64) void corr_kernel(
    const float* __restrict__ boxes, const int* __restrict__ labels,
    const int* __restrict__ valid,
    const float* __restrict__ cls3, const float* __restrict__ reg3, const float* __restrict__ obj3,
    const float* __restrict__ cls4, const float* __restrict__ reg4, const float* __restrict__ obj4,
    const float* __restrict__ cls5, const float* __restrict__ reg5, const float* __restrict__ obj5,
    float* __restrict__ ws) {
  int b = blockIdx.x;
  int m = threadIdx.x;
  __shared__ int s_cell[Mn];
  __shared__ int s_lab[Mn];

  float x1 = 0.f, y1 = 0.f, x2 = 0.f, y2 = 0.f;
  int lab = 0, val = 0;
  if (m < Mn) {
    const float* bp = boxes + ((size_t)b * Mn + m) * 4;
    x1 = bp[0]; y1 = bp[1]; x2 = bp[2]; y2 = bp[3];
    lab = labels[b * Mn + m];
    val = valid[b * Mn + m];
    s_lab[m] = lab;
  }

  for (int s = 0; s < 3; ++s) {
    const int W = (s == 0) ? 160 : ((s == 1) ? 80 : 40);
    const int H = W;
    const float stride = (s == 0) ? 8.f : ((s == 1) ? 16.f : 32.f);
    const float* clsP = (s == 0) ? cls3 : ((s == 1) ? cls4 : cls5);
    const float* regP = (s == 0) ? reg3 : ((s == 1) ? reg4 : reg5);
    const float* objP = (s == 0) ? obj3 : ((s == 1) ? obj4 : obj5);

    float cx = 0.f, cy = 0.f;
    int gx = 0, gy = 0, cell = -1;
    if (m < Mn && val > 0) {
      cx = (x1 + x2) * 0.5f / stride;
      cy = (y1 + y2) * 0.5f / stride;
      gx = min(max((int)cx, 0), W - 1);
      gy = min(max((int)cy, 0), H - 1);
      cell = gy * W + gx;
    }
    if (m < Mn) s_cell[m] = cell;
    __syncthreads();

    if (cell >= 0) {
      bool firstObj = true, lastReg = true, firstCls = true;
      for (int j = 0; j < Mn; ++j) {
        if (j == m) continue;
        if (s_cell[j] != cell) continue;
        if (j < m) {
          firstObj = false;
          if (s_lab[j] == lab) firstCls = false;
        } else {
          lastReg = false;   // a later valid box overwrites reg targets
        }
      }
      size_t plane = (size_t)H * W;
      size_t pix = (size_t)gy * W + gx;

      if (firstObj) {
        float x = objP[(size_t)b * plane + pix];
        float e = expf(-fabsf(x));
        float sp = fmaxf(x, 0.f) + log1pf(e);       // softplus(x)
        float corr = 1.5f * (sp - x) - sp;          // 1.5*sp(-x) - sp(x)
        atomicAdd(&ws[9 + s], corr);
        atomicAdd(&ws[15 + s], 4.0f);               // denom: 4 channels per cell
      }
      if (firstCls) {
        float x = clsP[((size_t)b * Cn + lab) * plane + pix];
        float e = expf(-fabsf(x));
        float sp = fmaxf(x, 0.f) + log1pf(e);       // softplus(x)
        float spn = sp - x;                         // softplus(-x)
        float p = (x >= 0.f) ? 1.f / (1.f + e) : e / (1.f + e);
        float q = 1.f - p;
        float corr = 0.25f * q * q * spn - 0.75f * p * p * sp;
        atomicAdd(&ws[6 + s], corr);
      }
      if (lastReg) {
        float w = fmaxf(x2 - x1, 1.f), h = fmaxf(y2 - y1, 1.f);
        float t0 = cx - (float)gx, t1 = cy - (float)gy;
        float t2 = logf(w / stride), t3 = logf(h / stride);
        const float* rp = regP + (size_t)b * 4 * plane + pix;
        float sum = 0.f, d, a;
        d = rp[0]         - t0; a = fabsf(d); sum += (a < 1.f) ? 0.5f * d * d : a - 0.5f;
        d = rp[plane]     - t1; a = fabsf(d); sum += (a < 1.f) ? 0.5f * d * d : a - 0.5f;
        d = rp[2 * plane] - t2; a = fabsf(d); sum += (a < 1.f) ? 0.5f * d * d : a - 0.5f;
        d = rp[3 * plane] - t3; a = fabsf(d); sum += (a < 1.f) ? 0.5f * d * d : a - 0.5f;
        atomicAdd(&ws[12 + s], sum);
      }
    }
    __syncthreads();
  }
}

__global__ void finalize_kernel(const float* __restrict__ ws, float* __restrict__ out) {
  if (threadIdx.x != 0 || blockIdx.x != 0) return;
  const float cls_cnt[3] = {6553600.f, 1638400.f, 409600.f};
  const float obj_cnt[3] = {1638400.f, 409600.f, 102400.f};
  float tc = 0.f, to = 0.f, tr = 0.f;
#pragma unroll
  for (int s = 0; s < 3; ++s) {
    tc += (ws[s] + ws[6 + s]) / cls_cnt[s];
    to += (ws[3 + s] + ws[9 + s]) / obj_cnt[s];
    float den = ws[15 + s];
    if (den > 0.f) tr += ws[12 + s] / fmaxf(den, 1.f);
  }
  float total = 2.5f * tc + 5.0f * tr + 0.5f * to;
  out[0] = total; out[1] = tc; out[2] = tr; out[3] = to;
}

extern "C" void kernel_launch(void* const* d_in, const int* in_sizes, int n_in,
                              void* d_out, int out_size, void* d_ws, size_t ws_size,
                              hipStream_t stream) {
  const float* cls3 = (const float*)d_in[0];
  const float* reg3 = (const float*)d_in[1];
  const float* obj3 = (const float*)d_in[2];
  const float* cls4 = (const float*)d_in[3];
  const float* reg4 = (const float*)d_in[4];
  const float* obj4 = (const float*)d_in[5];
  const float* cls5 = (const float*)d_in[6];
  const float* reg5 = (const float*)d_in[7];
  const float* obj5 = (const float*)d_in[8];
  const float* boxes = (const float*)d_in[9];
  const int* labels = (const int*)d_in[10];
  const int* valid = (const int*)d_in[11];
  float* ws = (float*)d_ws;
  float* out = (float*)d_out;

  hipMemsetAsync(d_ws, 0, 18 * sizeof(float), stream);

  base_kernel<<<2048, 256, 0, stream>>>(
      (const float4*)cls3, (const float4*)cls4, (const float4*)cls5,
      (const float4*)obj3, (const float4*)obj4, (const float4*)obj5, ws);

  corr_kernel<<<Bn, 64, 0, stream>>>(
      boxes, labels, valid,
      cls3, reg3, obj3, cls4, reg4, obj4, cls5, reg5, obj5, ws);

  finalize_kernel<<<1, 1, 0, stream>>>(ws, out);
}